// Round 1
// baseline (87.948 us; speedup 1.0000x reference)
//
#include <hip/hip_runtime.h>

// Problem constants (match reference setup_inputs)
#define B_    128
#define N_    32768
#define DMAX_ 16
#define ND_   8
#define NDX_  4
#define BN_   (B_ * N_)          // 4,194,304 elements per plane
#define SCALE_ 10.0f

// Output layout: [X (1), Xd (ND_), Xd_xarea (NDX_), new_threshold (1)] x (B,N)
// = 14 planes of BN_ float32 each.

__global__ __launch_bounds__(256) void alif_spikes_kernel(
    const float* __restrict__ V,
    const float* __restrict__ threshold,
    const float* __restrict__ alpha,
    const float* __restrict__ amplitude,
    const float* __restrict__ buffer,       // (DMAX_, B, N)
    const int*   __restrict__ delays,       // (ND_,)
    const int*   __restrict__ delays_x,     // (NDX_,)
    float*       __restrict__ out)          // (14, B, N)
{
    // Load all delay indices into registers. Addresses are uniform across the
    // wave -> compiler emits scalar loads; the d==0 branch below is
    // wave-uniform (no divergence).
    int d[ND_ + NDX_];
#pragma unroll
    for (int j = 0; j < ND_; ++j)  d[j]        = delays[j];
#pragma unroll
    for (int j = 0; j < NDX_; ++j) d[ND_ + j]  = delays_x[j];

    const int total4 = BN_ / 4;   // 1,048,576 float4 columns
    const int stride = gridDim.x * blockDim.x;

    for (int i = blockIdx.x * blockDim.x + threadIdx.x; i < total4; i += stride) {
        const int e = i * 4;              // flat element index within a plane
        const int n = e % N_;             // column (N_ % 4 == 0 so aligned)

        const float4 v  = *reinterpret_cast<const float4*>(V + e);
        const float4 th = *reinterpret_cast<const float4*>(threshold + e);
        const float4 al = *reinterpret_cast<const float4*>(alpha + n);
        const float4 am = *reinterpret_cast<const float4*>(amplitude + n);

        float4 X, nt;
        X.x = (v.x - th.x - 1.0f) >= 0.0f ? 1.0f : 0.0f;
        X.y = (v.y - th.y - 1.0f) >= 0.0f ? 1.0f : 0.0f;
        X.z = (v.z - th.z - 1.0f) >= 0.0f ? 1.0f : 0.0f;
        X.w = (v.w - th.w - 1.0f) >= 0.0f ? 1.0f : 0.0f;

        nt.x = th.x * al.x + X.x * am.x;
        nt.y = th.y * al.y + X.y * am.y;
        nt.z = th.z * al.z + X.z * am.z;
        nt.w = th.w * al.w + X.w * am.w;

        // plane 0: X
        *reinterpret_cast<float4*>(out + e) = X;

        // planes 1..12: delayed spikes. new_buffer[0] = X, new_buffer[k] =
        // buffer[k-1] for k >= 1.
#pragma unroll
        for (int j = 0; j < ND_ + NDX_; ++j) {
            const int dd = d[j];
            float4 val;
            if (dd == 0) {
                val = X;
            } else {
                val = *reinterpret_cast<const float4*>(
                    buffer + (size_t)(dd - 1) * BN_ + e);
            }
            *reinterpret_cast<float4*>(out + (size_t)(1 + j) * BN_ + e) = val;
        }

        // plane 13: new_threshold
        *reinterpret_cast<float4*>(out + (size_t)13 * BN_ + e) = nt;
    }
}

extern "C" void kernel_launch(void* const* d_in, const int* in_sizes, int n_in,
                              void* d_out, int out_size, void* d_ws, size_t ws_size,
                              hipStream_t stream) {
    const float* V         = (const float*)d_in[0];
    const float* threshold = (const float*)d_in[1];
    const float* alpha     = (const float*)d_in[2];
    const float* amplitude = (const float*)d_in[3];
    const float* buffer    = (const float*)d_in[4];
    const int*   delays    = (const int*)d_in[5];
    const int*   delays_x  = (const int*)d_in[6];
    float*       out       = (float*)d_out;

    const int total4 = BN_ / 4;
    const int block = 256;
    int grid = (total4 + block - 1) / block;
    if (grid > 2048) grid = 2048;   // grid-stride the rest

    alif_spikes_kernel<<<grid, block, 0, stream>>>(
        V, threshold, alpha, amplitude, buffer, delays, delays_x, out);
}

// Round 2
// 84.376 us; speedup vs baseline: 1.0423x; 1.0423x over previous
//
#include <hip/hip_runtime.h>

// Problem constants (match reference setup_inputs)
#define B_    128
#define N_    32768
#define DMAX_ 16
#define ND_   8
#define NDX_  4
#define BN_   (B_ * N_)          // 4,194,304 elements per plane

// Native vector type (works with __builtin_nontemporal_*)
typedef float f4 __attribute__((ext_vector_type(4)));

// Output layout: [X (1), Xd (ND_), Xd_xarea (NDX_), new_threshold (1)] x (B,N)
// = 14 planes of BN_ float32 each.

__global__ __launch_bounds__(256) void alif_spikes_kernel(
    const float* __restrict__ V,
    const float* __restrict__ threshold,
    const float* __restrict__ alpha,
    const float* __restrict__ amplitude,
    const float* __restrict__ buffer,       // (DMAX_, B, N)
    const int*   __restrict__ delays,       // (ND_,)
    const int*   __restrict__ delays_x,     // (NDX_,)
    float*       __restrict__ out)          // (14, B, N)
{
    // Wave-uniform delay indices -> scalar loads, uniform branches.
    int d[ND_ + NDX_];
#pragma unroll
    for (int j = 0; j < ND_; ++j)  d[j]       = delays[j];
#pragma unroll
    for (int j = 0; j < NDX_; ++j) d[ND_ + j] = delays_x[j];

    // Exact-fit grid: one float4 chunk per thread, no loop.
    const int i = blockIdx.x * blockDim.x + threadIdx.x;   // [0, BN_/4)
    const int e = i * 4;              // flat element index within a plane
    const int n = e & (N_ - 1);       // column (N_ pow2, % 4 == 0 so aligned)

    // Streaming (read-once) inputs: non-temporal.
    const f4 v  = __builtin_nontemporal_load(reinterpret_cast<const f4*>(V + e));
    const f4 th = __builtin_nontemporal_load(reinterpret_cast<const f4*>(threshold + e));
    // Heavily reused (B=128x) small vectors: normal cached loads.
    const f4 al = *reinterpret_cast<const f4*>(alpha + n);
    const f4 am = *reinterpret_cast<const f4*>(amplitude + n);

    f4 X, nt;
#pragma unroll
    for (int c = 0; c < 4; ++c) {
        X[c]  = (v[c] - th[c] - 1.0f) >= 0.0f ? 1.0f : 0.0f;
        nt[c] = th[c] * al[c] + X[c] * am[c];
    }

    // plane 0: X
    __builtin_nontemporal_store(X, reinterpret_cast<f4*>(out + e));

    // planes 1..12: delayed spikes. new_buffer[0] = X, new_buffer[k] = buffer[k-1].
#pragma unroll
    for (int j = 0; j < ND_ + NDX_; ++j) {
        const int dd = d[j];
        f4 val;
        if (dd == 0) {
            val = X;
        } else {
            val = __builtin_nontemporal_load(reinterpret_cast<const f4*>(
                buffer + (size_t)(dd - 1) * BN_ + e));
        }
        __builtin_nontemporal_store(val,
            reinterpret_cast<f4*>(out + (size_t)(1 + j) * BN_ + e));
    }

    // plane 13: new_threshold
    __builtin_nontemporal_store(nt, reinterpret_cast<f4*>(out + (size_t)13 * BN_ + e));
}

extern "C" void kernel_launch(void* const* d_in, const int* in_sizes, int n_in,
                              void* d_out, int out_size, void* d_ws, size_t ws_size,
                              hipStream_t stream) {
    const float* V         = (const float*)d_in[0];
    const float* threshold = (const float*)d_in[1];
    const float* alpha     = (const float*)d_in[2];
    const float* amplitude = (const float*)d_in[3];
    const float* buffer    = (const float*)d_in[4];
    const int*   delays    = (const int*)d_in[5];
    const int*   delays_x  = (const int*)d_in[6];
    float*       out       = (float*)d_out;

    const int total4 = BN_ / 4;          // 1,048,576 chunks
    const int block  = 256;
    const int grid   = total4 / block;   // 4096 blocks, exact fit

    alif_spikes_kernel<<<grid, block, 0, stream>>>(
        V, threshold, alpha, amplitude, buffer, delays, delays_x, out);
}

// Round 3
// 76.034 us; speedup vs baseline: 1.1567x; 1.1097x over previous
//
#include <hip/hip_runtime.h>

// Problem constants (match reference setup_inputs)
#define B_    128
#define N_    32768
#define DMAX_ 16
#define ND_   8
#define NDX_  4
#define BN_   (B_ * N_)          // 4,194,304 elements per plane

typedef float f4 __attribute__((ext_vector_type(4)));

// Output layout: [X (1), Xd (ND_), Xd_xarea (NDX_), new_threshold (1)] x (B,N)
// = 14 planes of BN_ float32 each.
//
// Plane-major decomposition: blockIdx.y = task.
//   task 0      : read V,th (+alpha,amplitude) -> write plane 0 (X) and plane 13 (nt)
//   task 1..12  : pure copy buffer[dd-1] -> plane task   (dd==0: recompute X)
// Each block is a 1-in/1-out contiguous stream -> DRAM-row-friendly copy pattern.

__global__ __launch_bounds__(256) void alif_planes_kernel(
    const float* __restrict__ V,
    const float* __restrict__ threshold,
    const float* __restrict__ alpha,
    const float* __restrict__ amplitude,
    const float* __restrict__ buffer,       // (DMAX_, B, N)
    const int*   __restrict__ delays,       // (ND_,)
    const int*   __restrict__ delays_x,     // (NDX_,)
    float*       __restrict__ out)          // (14, B, N)
{
    const int task = blockIdx.y;                              // 0..12
    const int i    = blockIdx.x * blockDim.x + threadIdx.x;   // [0, BN_/4)
    const int e    = i * 4;                                   // element within plane
    const int n    = e & (N_ - 1);                            // column index

    if (task == 0) {
        // Compute planes: X (plane 0) and new_threshold (plane 13).
        const f4 v  = __builtin_nontemporal_load(reinterpret_cast<const f4*>(V + e));
        const f4 th = __builtin_nontemporal_load(reinterpret_cast<const f4*>(threshold + e));
        const f4 al = *reinterpret_cast<const f4*>(alpha + n);      // L2-resident, reused
        const f4 am = *reinterpret_cast<const f4*>(amplitude + n);

        f4 X, nt;
#pragma unroll
        for (int c = 0; c < 4; ++c) {
            X[c]  = (v[c] - th[c] - 1.0f) >= 0.0f ? 1.0f : 0.0f;
            nt[c] = th[c] * al[c] + X[c] * am[c];
        }
        __builtin_nontemporal_store(X,  reinterpret_cast<f4*>(out + e));
        __builtin_nontemporal_store(nt, reinterpret_cast<f4*>(out + (size_t)13 * BN_ + e));
    } else {
        // Copy planes 1..12. Wave-uniform delay (scalar load + uniform branch).
        const int j  = task;                                  // output plane index
        const int dd = (j <= ND_) ? delays[j - 1] : delays_x[j - 1 - ND_];

        f4 val;
        if (dd == 0) {
            // new_buffer[0] == X : recompute from V, threshold.
            const f4 v  = __builtin_nontemporal_load(reinterpret_cast<const f4*>(V + e));
            const f4 th = __builtin_nontemporal_load(reinterpret_cast<const f4*>(threshold + e));
#pragma unroll
            for (int c = 0; c < 4; ++c)
                val[c] = (v[c] - th[c] - 1.0f) >= 0.0f ? 1.0f : 0.0f;
        } else {
            val = __builtin_nontemporal_load(reinterpret_cast<const f4*>(
                buffer + (size_t)(dd - 1) * BN_ + e));
        }
        __builtin_nontemporal_store(val, reinterpret_cast<f4*>(out + (size_t)j * BN_ + e));
    }
}

extern "C" void kernel_launch(void* const* d_in, const int* in_sizes, int n_in,
                              void* d_out, int out_size, void* d_ws, size_t ws_size,
                              hipStream_t stream) {
    const float* V         = (const float*)d_in[0];
    const float* threshold = (const float*)d_in[1];
    const float* alpha     = (const float*)d_in[2];
    const float* amplitude = (const float*)d_in[3];
    const float* buffer    = (const float*)d_in[4];
    const int*   delays    = (const int*)d_in[5];
    const int*   delays_x  = (const int*)d_in[6];
    float*       out       = (float*)d_out;

    const int block  = 256;
    const int gridX  = (BN_ / 4) / block;   // 4096 blocks per plane, exact fit
    dim3 grid(gridX, 1 + ND_ + NDX_);       // 13 tasks (task 0 writes 2 planes)

    alif_planes_kernel<<<grid, dim3(block), 0, stream>>>(
        V, threshold, alpha, amplitude, buffer, delays, delays_x, out);
}